// Round 2
// baseline (281.307 us; speedup 1.0000x reference)
//
#include <hip/hip_runtime.h>

#define NC 91
#define NBIN 182          // bins 0..90 = union counts, 91..181 = intersection counts
#define NCOL 8            // lane-column replication within a wave
#define NB 32
#define HW (1024 * 1024)
#define PIX_PER_BLOCK 4096   // 256 threads * 4 int4 loads * 4 ints

__global__ __launch_bounds__(256) void hist_kernel(const int* __restrict__ x,
                                                   const int* __restrict__ t,
                                                   int* __restrict__ g_hist) {
    // per-wave histogram, 8 columns; column = lane%8 so bank = 8*(bin%4)+col
    __shared__ int s_h[4][NBIN * NCOL];

    const int tid = threadIdx.x;
    int* sf = &s_h[0][0];
    for (int i = tid; i < 4 * NBIN * NCOL; i += 256) sf[i] = 0;
    __syncthreads();

    const int wave = tid >> 6;
    const int col  = tid & (NCOL - 1);
    int* h = s_h[wave];

    const int b = blockIdx.y;
    const long base = (long)b * HW + (long)blockIdx.x * PIX_PER_BLOCK;
    const int4* __restrict__ x4 = (const int4*)(x + base);
    const int4* __restrict__ t4 = (const int4*)(t + base);

#pragma unroll
    for (int i = 0; i < 4; ++i) {
        int4 xv = x4[i * 256 + tid];
        int4 tv = t4[i * 256 + tid];
        // union[x] += 1 always; second increment: inter[x] if match else union[t]
        int b0 = xv.x, b1 = xv.y, b2 = xv.z, b3 = xv.w;
        int c0 = (xv.x == tv.x) ? (NC + xv.x) : tv.x;
        int c1 = (xv.y == tv.y) ? (NC + xv.y) : tv.y;
        int c2 = (xv.z == tv.z) ? (NC + xv.z) : tv.z;
        int c3 = (xv.w == tv.w) ? (NC + xv.w) : tv.w;
        atomicAdd(&h[b0 * NCOL + col], 1);
        atomicAdd(&h[c0 * NCOL + col], 1);
        atomicAdd(&h[b1 * NCOL + col], 1);
        atomicAdd(&h[c1 * NCOL + col], 1);
        atomicAdd(&h[b2 * NCOL + col], 1);
        atomicAdd(&h[c2 * NCOL + col], 1);
        atomicAdd(&h[b3 * NCOL + col], 1);
        atomicAdd(&h[c3 * NCOL + col], 1);
    }
    __syncthreads();

    // reduce 4 waves x 8 columns per bin, flush to global
    for (int c = tid; c < NBIN; c += 256) {
        int s = 0;
#pragma unroll
        for (int w = 0; w < 4; ++w) {
#pragma unroll
            for (int k = 0; k < NCOL; ++k) s += s_h[w][c * NCOL + k];
        }
        if (s) atomicAdd(&g_hist[b * NBIN + c], s);
    }
}

__global__ __launch_bounds__(64) void finalize_kernel(const int* __restrict__ g_hist,
                                                      const float* __restrict__ smooth,
                                                      float* __restrict__ out) {
    const int b = blockIdx.x;
    const int lane = threadIdx.x;  // 0..63
    const float s = smooth[0];
    float acc = 0.0f;
    for (int c = lane; c < NC; c += 64) {
        float un = (float)g_hist[b * NBIN + c];
        float in = (float)g_hist[b * NBIN + NC + c];
        acc += (in + s) / (un + s);
    }
#pragma unroll
    for (int off = 32; off > 0; off >>= 1)
        acc += __shfl_down(acc, off, 64);
    if (lane == 0) out[b] = acc / (float)NC;
}

extern "C" void kernel_launch(void* const* d_in, const int* in_sizes, int n_in,
                              void* d_out, int out_size, void* d_ws, size_t ws_size,
                              hipStream_t stream) {
    const int* x = (const int*)d_in[0];
    const int* t = (const int*)d_in[1];
    const float* smooth = (const float*)d_in[2];
    float* out = (float*)d_out;

    int* g_hist = (int*)d_ws;

    hipMemsetAsync(d_ws, 0, NB * NBIN * sizeof(int), stream);

    dim3 grid(HW / PIX_PER_BLOCK, NB);  // 256 x 32 blocks
    hist_kernel<<<grid, 256, 0, stream>>>(x, t, g_hist);
    finalize_kernel<<<NB, 64, 0, stream>>>(g_hist, smooth, out);
}

// Round 3
// 281.159 us; speedup vs baseline: 1.0005x; 1.0005x over previous
//
#include <hip/hip_runtime.h>

#define NC 91
#define NBIN 182          // bins 0..90 = union counts, 91..181 = intersection counts
#define NB 32
#define HW (1024 * 1024)
#define NT 256            // threads per block
#define PPT 64            // pixels per thread (max per-bin count = 64 < 255, u8 safe)
#define PIX_PER_BLOCK (NT * PPT)   // 16384
#define STRIDE 260        // bytes per bin row: 256 data + 4 pad -> bank=(bin+lane/4)%32

__global__ __launch_bounds__(256) void hist_kernel(const int* __restrict__ x,
                                                   const int* __restrict__ t,
                                                   int* __restrict__ g_hist) {
    // Per-THREAD private byte counters: no atomics, no cross-lane aliasing.
    // s_h[bin*STRIDE + tid]
    __shared__ unsigned char s_h[NBIN * STRIDE];  // 47,320 B

    const int tid = threadIdx.x;

    // zero-init (11,830 dwords)
    {
        unsigned int* p = (unsigned int*)s_h;
        for (int i = tid; i < NBIN * STRIDE / 4; i += NT) p[i] = 0u;
    }
    __syncthreads();

    unsigned char* h = s_h + tid;  // this thread's byte column

    const int b = blockIdx.y;
    const long base = (long)b * HW + (long)blockIdx.x * PIX_PER_BLOCK;
    const int4* __restrict__ x4 = (const int4*)(x + base);
    const int4* __restrict__ t4 = (const int4*)(t + base);

#pragma unroll 4
    for (int i = 0; i < PPT / 4; ++i) {
        int4 xv = x4[i * NT + tid];
        int4 tv = t4[i * NT + tid];
        // increment 1: union[x]; increment 2: inter[x] if match else union[t]
        // the two bins of one pixel are always distinct -> independent RMW chains
        int u0 = xv.x, u1 = xv.y, u2 = xv.z, u3 = xv.w;
        int v0 = (xv.x == tv.x) ? (NC + xv.x) : tv.x;
        int v1 = (xv.y == tv.y) ? (NC + xv.y) : tv.y;
        int v2 = (xv.z == tv.z) ? (NC + xv.z) : tv.z;
        int v3 = (xv.w == tv.w) ? (NC + xv.w) : tv.w;
        h[u0 * STRIDE] += 1;
        h[v0 * STRIDE] += 1;
        h[u1 * STRIDE] += 1;
        h[v1 * STRIDE] += 1;
        h[u2 * STRIDE] += 1;
        h[v2 * STRIDE] += 1;
        h[u3 * STRIDE] += 1;
        h[v3 * STRIDE] += 1;
    }
    __syncthreads();

    // flush: thread c sums 256 bytes of bin c (64 dwords), one global atomic per bin
    for (int c = tid; c < NBIN; c += NT) {
        const unsigned int* row = (const unsigned int*)(s_h + c * STRIDE);
        unsigned int s = 0;
#pragma unroll
        for (int k = 0; k < 64; ++k) {
            unsigned int d = row[k];
#if __has_builtin(__builtin_amdgcn_udot4)
            s = __builtin_amdgcn_udot4(d, 0x01010101u, s, false);
#else
            s += (d & 0xffu) + ((d >> 8) & 0xffu) + ((d >> 16) & 0xffu) + (d >> 24);
#endif
        }
        atomicAdd(&g_hist[b * NBIN + c], (int)s);
    }
}

__global__ __launch_bounds__(64) void finalize_kernel(const int* __restrict__ g_hist,
                                                      const float* __restrict__ smooth,
                                                      float* __restrict__ out) {
    const int b = blockIdx.x;
    const int lane = threadIdx.x;  // 0..63
    const float s = smooth[0];
    float acc = 0.0f;
    for (int c = lane; c < NC; c += 64) {
        float un = (float)g_hist[b * NBIN + c];
        float in = (float)g_hist[b * NBIN + NC + c];
        acc += (in + s) / (un + s);
    }
#pragma unroll
    for (int off = 32; off > 0; off >>= 1)
        acc += __shfl_down(acc, off, 64);
    if (lane == 0) out[b] = acc / (float)NC;
}

extern "C" void kernel_launch(void* const* d_in, const int* in_sizes, int n_in,
                              void* d_out, int out_size, void* d_ws, size_t ws_size,
                              hipStream_t stream) {
    const int* x = (const int*)d_in[0];
    const int* t = (const int*)d_in[1];
    const float* smooth = (const float*)d_in[2];
    float* out = (float*)d_out;

    int* g_hist = (int*)d_ws;

    hipMemsetAsync(d_ws, 0, NB * NBIN * sizeof(int), stream);

    dim3 grid(HW / PIX_PER_BLOCK, NB);  // 64 x 32 = 2048 blocks
    hist_kernel<<<grid, NT, 0, stream>>>(x, t, g_hist);
    finalize_kernel<<<NB, 64, 0, stream>>>(g_hist, smooth, out);
}